// Round 12
// baseline (90.806 us; speedup 1.0000x reference)
//
#include <hip/hip_runtime.h>
#include <math.h>

typedef unsigned short ushort_t;
typedef unsigned int uint32_tt;
typedef __attribute__((ext_vector_type(8))) short bf16x8;
typedef __attribute__((ext_vector_type(4))) float f32x4;

#define NR   8
#define NK   10
#define ND   256
#define NDL  10
#define NB   4096
#define NN   100
#define NP   128      // phase-1 padded n (8*16), rows 100..127 zero
#define NP2  128      // phase-3 padded K over n (4*32)

// ---- workspace layout (bytes) ---- (R15 layout, xb kept)
#define WS_GP   0                          // fp32 Gp[8][1000]
#define WS_XB   32768                      // bf16 x[4096][256] = 2,097,152
#define WS_U1   (32768 + 2097152)          // bf16 U1[8][128][256] = 524288
#define WS_U2   (WS_U1 + 524288)           // bf16 U2[8][256][128] = 524288
#define WS_NEED (WS_U2 + 524288)           // 3,178,496

// ---- ksub LDS layout (bytes) — R18 diet: 4 blocks/CU ----
#define L_US   0            // staged U slice: 64 rows x 272B = 17408
#define L_ZB   17408        // zbuf: 32 x 100 f32 = 12800 (wt overlay)
#define L_GP   30208        // gp: 1000 f32
#define L_SIZE 34208        // 4 x 34208 = 136832 <= 160K -> 4 blocks/CU

__device__ __forceinline__ ushort_t f2bf(float f) {
    uint32_tt u = __float_as_uint(f);
    u = (u + 0x7FFF + ((u >> 16) & 1)) >> 16;   // RNE
    return (ushort_t)u;
}

// =====================================================================
// Prep, grid 336 x 256 (R15-verified, verbatim):
//  bid < 80 : one block per (r,k): Gram + U1 (128-row pad) + U2.
//  bid >= 80: 256 blocks, x->bf16 (xb kept — f32-direct x regressed
//             twice: R14, R16).
// =====================================================================
__global__ __launch_bounds__(256) void prep_kernel(const float* __restrict__ x,
                                                   const float* __restrict__ Us,
                                                   char* __restrict__ ws) {
    __shared__ float lu[ND * NDL];     // 10 KB, layout [D][d] stride 10
    const int bid = blockIdx.x, tid = threadIdx.x;

    if (bid >= 80) {
        ushort_t* xb = (ushort_t*)(ws + WS_XB);
        const int base = (bid - 80) * 1024;
        #pragma unroll
        for (int v = 0; v < 4; ++v) {
            int i = base + v * 256 + tid;
            float4 vv = ((const float4*)x)[i];
            uint32_tt p0 = (uint32_tt)f2bf(vv.x) | ((uint32_tt)f2bf(vv.y) << 16);
            uint32_tt p1 = (uint32_tt)f2bf(vv.z) | ((uint32_tt)f2bf(vv.w) << 16);
            ((uint2*)xb)[i] = make_uint2(p0, p1);
        }
        return;
    }

    const int rk = bid;                      // 0..79
    const int r  = rk / NK, k = rk - r * NK;
    const float* U = Us + (size_t)rk * ND * NDL;
    for (int i = tid; i < 640; i += 256)
        ((float4*)lu)[i] = ((const float4*)U)[i];
    __syncthreads();

    // ---- Gram: Gp = 10*I - 5*U^T U ----
    float* Gp = (float*)(ws + WS_GP);
    if (tid < NDL * NDL) {
        int d1 = tid / NDL, d2 = tid - d1 * NDL;
        float acc = 0.f;
        #pragma unroll 8
        for (int Di = 0; Di < ND; ++Di)
            acc += lu[Di * NDL + d1] * lu[Di * NDL + d2];
        Gp[(size_t)rk * 100 + tid] = (d1 == d2 ? 10.0f : 0.0f) - 5.0f * acc;
    }

    // ---- U1[r][k*10+d][D] bf16, coalesced in D ----
    ushort_t* u1 = (ushort_t*)(ws + WS_U1);
    for (int p = tid; p < ND * NDL; p += 256) {
        int d = p >> 8, D = p & 255;
        u1[((size_t)r * NP + k * NDL + d) * ND + D] = f2bf(lu[D * NDL + d]);
    }

    // ---- U2[r][D][k*10..k*10+10) bf16 ----
    ushort_t* u2 = (ushort_t*)(ws + WS_U2);
    {
        int D = tid;
        uint32_tt* dst = (uint32_tt*)(u2 + ((size_t)r * ND + D) * NP2 + k * NDL);
        const float* src = lu + D * NDL;
        #pragma unroll
        for (int j = 0; j < 5; ++j)
            dst[j] = (uint32_tt)f2bf(src[2 * j]) | ((uint32_tt)f2bf(src[2 * j + 1]) << 16);
    }

    // ---- zero pads (k==9 block only) ----
    if (k == NK - 1) {
        for (int p = tid; p < 28 * ND; p += 256) {
            int n = p >> 8, D = p & 255;
            u1[((size_t)r * NP + 100 + n) * ND + D] = 0;
        }
        uint32_tt* u2u = (uint32_tt*)u2;
        #pragma unroll
        for (int j = 0; j < 14; ++j)
            u2u[((size_t)r * ND + tid) * (NP2 / 2) + 50 + j] = 0;
    }
}

// =====================================================================
// R18 "occupancy" ksub: staged body on an LDS diet -> 4 blocks/CU.
// Diagnosis: R13/R15/R17 (staged, 2/2/1 blocks/CU) all ~86-90; every
// counter read shows all pipes idle -> latency-bound. Only untried
// lever: TLP. Grid 1024 x 256 (R0's XCD-clustered mapping), 32 b-rows
// per block; U staged in 64-row x 272B slices (17.4KB) -> LDS 33.4KB
// -> 4 blocks/CU = 4 waves/SIMD (2x R15's latency hiding).
// U1: 4 slices (n-half x D-half); U2: 4 D-quarter slices. Next slice's
// loads issued before current MFMA (R15 prefetch); U2 slice-0 issued
// before softmax. All fragment mappings / softmax body R0-proven.
// =====================================================================
__global__ __launch_bounds__(256, 2) void ksub_occ(const char* __restrict__ ws,
                                                   float* __restrict__ out) {
    __shared__ __align__(16) char smem[L_SIZE];
    char*  usb = smem + L_US;
    float* zb  = (float*)(smem + L_ZB);
    ushort_t* wt = (ushort_t*)(smem + L_ZB);       // overlay after zb reads
    float* gp  = (float*)(smem + L_GP);

    const int tid  = threadIdx.x;
    const int w    = tid >> 6;
    const int lane = tid & 63;
    const int c    = lane & 15;
    const int q    = lane >> 4;
    const int bid  = blockIdx.x;
    const int xcd  = bid & 7;
    const int idx  = bid >> 3;                 // 0..127
    const int r    = idx & 7;
    const int b0   = (xcd * 16 + (idx >> 3)) * 32;
    const int bloc = (w & 1) * 16 + c;         // 0..31
    const int pair = w >> 1;                   // 0/1

    const ushort_t* xbp = (const ushort_t*)(ws + WS_XB) + (size_t)(b0 + bloc) * ND + q * 8;
    const ushort_t* u1b = (const ushort_t*)(ws + WS_U1) + (size_t)r * NP * ND;
    const ushort_t* u2b = (const ushort_t*)(ws + WS_U2) + (size_t)r * ND * NP2;
    const float*    gpg = (const float*)(ws + WS_GP) + (size_t)r * 1000;

    for (int i = tid; i < 1000; i += 256) gp[i] = gpg[i];

    // staging lane mapping: 64 rows x 16 chunks = 1024 chunks, 4/thread
    const int sn = tid >> 4;           // base row (advance by 16 per j)
    const int sm = tid & 15;           // 16B chunk in 256B slice row

    bf16x8 sA[4], sB[4];

    // U1 slice s (h1=s>>1 row-half, h2=s&1 D-half)
    #define LD_U1(dst, s) { \
        const int h1 = (s) >> 1, h2 = (s) & 1; \
        _Pragma("unroll") \
        for (int j = 0; j < 4; ++j) \
            dst[j] = *(const bf16x8*)(u1b + (size_t)(h1 * 64 + sn + j * 16) * ND + h2 * 128 + sm * 8); \
    }
    // U2 slice g (D-out rows [64g,64g+64))
    #define LD_U2(dst, g) { \
        _Pragma("unroll") \
        for (int j = 0; j < 4; ++j) \
            dst[j] = *(const bf16x8*)(u2b + (size_t)((g) * 64 + sn + j * 16) * NP2 + sm * 8); \
    }
    #define ST_U(src) { \
        _Pragma("unroll") \
        for (int j = 0; j < 4; ++j) \
            *(bf16x8*)(usb + (sn + j * 16) * 272 + sm * 16) = src[j]; \
    }

    // ---- x fragments upfront (full D, bf16 xb) ----
    bf16x8 xfr[8];
    #pragma unroll
    for (int d = 0; d < 8; ++d)
        xfr[d] = *(const bf16x8*)(xbp + d * 32);

    // ================= phase 1: z = U1^T x, 4 slices =================
    f32x4 acc1[4];
    #pragma unroll
    for (int t = 0; t < 4; ++t) acc1[t] = (f32x4){0.f, 0.f, 0.f, 0.f};

    // per slice: MFMA over tt in {0,1}, acc index h1*2+tt, x-chunk h2*4+d
    #define MM1(s) { \
        const int h1 = (s) >> 1, h2 = (s) & 1; \
        _Pragma("unroll") \
        for (int tt = 0; tt < 2; ++tt) { \
            _Pragma("unroll") \
            for (int d = 0; d < 4; ++d) { \
                bf16x8 uf = *(const bf16x8*)(usb + ((pair * 2 + tt) * 16 + c) * 272 + d * 64 + q * 16); \
                acc1[h1 * 2 + tt] = __builtin_amdgcn_mfma_f32_16x16x32_bf16(uf, xfr[h2 * 4 + d], acc1[h1 * 2 + tt], 0, 0, 0); \
            } \
        } \
    }

    LD_U1(sA, 0);
    ST_U(sA); __syncthreads();
    LD_U1(sB, 1);
    MM1(0); __syncthreads();
    ST_U(sB); __syncthreads();
    LD_U1(sA, 2);
    MM1(1); __syncthreads();
    ST_U(sA); __syncthreads();
    LD_U1(sB, 3);
    MM1(2); __syncthreads();
    ST_U(sB); __syncthreads();
    MM1(3);

    // ---- dump Z^T C-frags: global t = h1*4 + pair*2 + tt ----
    #pragma unroll
    for (int h1 = 0; h1 < 2; ++h1) {
        #pragma unroll
        for (int tt = 0; tt < 2; ++tt) {
            int t = h1 * 4 + pair * 2 + tt;
            #pragma unroll
            for (int rg = 0; rg < 4; ++rg) {
                int n = t * 16 + q * 4 + rg;
                if (n < NN) zb[bloc * 100 + n] = acc1[h1 * 2 + tt][rg];
            }
        }
    }
    __syncthreads();               // zb visible; usb reads done

    // ---- issue U2 slice 0 loads (latency hides under softmax) ----
    LD_U2(sA, 0);

    // ================= softmax (R0-proven body, 1 tile) =================
    {
        const int bsm = tid >> 3;
        const int kq  = tid & 7;
        float zk[2][10], ee[2];
        {
            const float* zr = zb + bsm * 100;
            float L[2];
            #pragma unroll
            for (int jj = 0; jj < 2; ++jj) {
                int k = kq + 8 * jj;
                L[jj] = -1e30f;
                if (k < NK) {
                    #pragma unroll
                    for (int d = 0; d < 10; ++d) zk[jj][d] = zr[k * 10 + d];
                    const float* g = gp + k * 100;
                    float acc = 0.f;
                    #pragma unroll
                    for (int d1 = 0; d1 < 10; ++d1) {
                        float t2 = 0.f;
                        #pragma unroll
                        for (int d2 = 0; d2 < 10; ++d2) t2 += g[d1 * 10 + d2] * zk[jj][d2];
                        acc += t2 * zk[jj][d1];
                    }
                    L[jj] = acc;
                }
            }
            float m = fmaxf(L[0], L[1]);
            m = fmaxf(m, __shfl_xor(m, 1));
            m = fmaxf(m, __shfl_xor(m, 2));
            m = fmaxf(m, __shfl_xor(m, 4));
            float s = 0.f;
            #pragma unroll
            for (int jj = 0; jj < 2; ++jj) {
                ee[jj] = (kq + 8 * jj < NK) ? __expf(L[jj] - m) : 0.f;
                s += ee[jj];
            }
            s += __shfl_xor(s, 1);
            s += __shfl_xor(s, 2);
            s += __shfl_xor(s, 4);
            float inv = 1.0f / s;
            #pragma unroll
            for (int jj = 0; jj < 2; ++jj) ee[jj] *= inv;
        }
        __syncthreads();           // zb reads done; wt overlay safe

        #pragma unroll
        for (int jj = 0; jj < 2; ++jj) {
            int k = kq + 8 * jj;
            if (k < NK) {
                #pragma unroll
                for (int d = 0; d < 10; ++d)
                    wt[bsm * 136 + k * 10 + d] = f2bf(ee[jj] * zk[jj][d]);
            }
        }
        // zero-pad wt n in [100,128): 14 uints per row, 32 rows
        {
            int row = tid >> 4, p = tid & 15;
            if (p < 14) ((uint32_tt*)wt)[row * 68 + 50 + p] = 0;
            row = (tid + 256) >> 4;
            if (p < 14) ((uint32_tt*)wt)[row * 68 + 50 + p] = 0;
        }
    }
    __syncthreads();               // wt complete

    // ================= phase 3: out = U2 w, 4 D-quarter slices =============
    const size_t orow = (size_t)r * NB + b0 + bloc;
    f32x4 acc3[2];

    #define MM3ST(g) { \
        acc3[0] = (f32x4){0.f, 0.f, 0.f, 0.f}; \
        acc3[1] = (f32x4){0.f, 0.f, 0.f, 0.f}; \
        _Pragma("unroll") \
        for (int nc = 0; nc < 4; ++nc) { \
            bf16x8 bfr = *(const bf16x8*)(wt + bloc * 136 + nc * 32 + q * 8); \
            _Pragma("unroll") \
            for (int jj = 0; jj < 2; ++jj) { \
                bf16x8 af = *(const bf16x8*)(usb + ((pair * 2 + jj) * 16 + c) * 272 + nc * 64 + q * 16); \
                acc3[jj] = __builtin_amdgcn_mfma_f32_16x16x32_bf16(af, bfr, acc3[jj], 0, 0, 0); \
            } \
        } \
        _Pragma("unroll") \
        for (int jj = 0; jj < 2; ++jj) \
            __builtin_nontemporal_store(acc3[jj], \
                (f32x4*)(out + orow * ND + ((g) * 4 + pair * 2 + jj) * 16 + q * 4)); \
    }

    ST_U(sA); __syncthreads();
    LD_U2(sB, 1);
    MM3ST(0); __syncthreads();
    ST_U(sB); __syncthreads();
    LD_U2(sA, 2);
    MM3ST(1); __syncthreads();
    ST_U(sA); __syncthreads();
    LD_U2(sB, 3);
    MM3ST(2); __syncthreads();
    ST_U(sB); __syncthreads();
    MM3ST(3);

    #undef LD_U1
    #undef LD_U2
    #undef ST_U
    #undef MM1
    #undef MM3ST
}

// =====================================================================
// Fallback (round-2 verified path) if ws is too small for staging
// =====================================================================
#define XS_S 68
#define US_S 132
#define ZB_S 104
#define WT_S 68
#define U2_S 68
#define OFF_WT 0
#define OFF_SH 6800
#define OFF_GP 13600
#define SMEM_F 14600

__global__ __launch_bounds__(128) void gram_kernel(const float* __restrict__ Us,
                                                   float* __restrict__ Gp) {
    int rk = blockIdx.x;
    const float* U = Us + (size_t)rk * ND * NDL;
    __shared__ float u[ND * NDL];
    for (int i = threadIdx.x; i < ND * NDL; i += blockDim.x) u[i] = U[i];
    __syncthreads();
    int e = threadIdx.x;
    if (e < NDL * NDL) {
        int d1 = e / NDL, d2 = e % NDL;
        float acc = 0.f;
        #pragma unroll 8
        for (int Di = 0; Di < ND; ++Di)
            acc += u[Di * NDL + d1] * u[Di * NDL + d2];
        Gp[(size_t)rk * (NDL * NDL) + e] = (d1 == d2 ? 10.0f : 0.0f) - 5.0f * acc;
    }
}

__global__ __launch_bounds__(256, 2) void ksub_fused(const float* __restrict__ x,
                                                     const float* __restrict__ Us,
                                                     const float* __restrict__ Gp,
                                                     float* __restrict__ out) {
    __shared__ float smemf[SMEM_F];
    float* wT   = smemf + OFF_WT;
    float* xsf  = smemf + OFF_SH;
    float* usf  = smemf + OFF_SH + 2176;
    float* zbuf = smemf + OFF_SH;
    float* u2   = smemf + OFF_SH;
    float* gp   = smemf + OFF_GP;

    const int tid = threadIdx.x;
    const int r   = blockIdx.y;
    const int b0  = blockIdx.x * 64;

    for (int i = tid; i < NK * NDL * NDL; i += 256)
        gp[i] = Gp[(size_t)r * (NK * NDL * NDL) + i];

    const int nt = tid & 15;
    const int bt = tid >> 4;
    float acc[4][8];
    #pragma unroll
    for (int j = 0; j < 4; ++j)
        #pragma unroll
        for (int i = 0; i < 8; ++i) acc[j][i] = 0.f;

    for (int cch = 0; cch < 8; ++cch) {
        __syncthreads();
        for (int i = tid; i < 512; i += 256) {
            int b = i >> 3, f = i & 7;
            float4 v = ((const float4*)(x + (size_t)(b0 + b) * ND))[cch * 8 + f];
            float* dst = xsf + (f * 4) * XS_S + b;
            dst[0] = v.x; dst[XS_S] = v.y; dst[2 * XS_S] = v.z; dst[3 * XS_S] = v.w;
        }
        for (int p = tid; p < 320; p += 256) {
            int k = p >> 5, Dl = p & 31;
            const float* g = Us + ((size_t)((r * NK + k) * ND) + cch * 32 + Dl) * NDL;
            float* dst = usf + Dl * US_S + k * NDL;
            #pragma unroll
            for (int d = 0; d < 10; ++d) dst[d] = g[d];
        }
        __syncthreads();
        #pragma unroll 4
        for (int Dl = 0; Dl < 32; ++Dl) {
            float4 xv = *(const float4*)(xsf + Dl * XS_S + bt * 4);
            float4 ua = *(const float4*)(usf + Dl * US_S + nt * 8);
            float4 ub = *(const float4*)(usf + Dl * US_S + nt * 8 + 4);
            float xa[4] = {xv.x, xv.y, xv.z, xv.w};
            float uu[8] = {ua.x, ua.y, ua.z, ua.w, ub.x, ub.y, ub.z, ub.w};
            #pragma unroll
            for (int j = 0; j < 4; ++j)
                #pragma unroll
                for (int i = 0; i < 8; ++i) acc[j][i] += xa[j] * uu[i];
        }
    }
    __syncthreads();
    if (nt < 12) {
        #pragma unroll
        for (int j = 0; j < 4; ++j) {
            float* zp = zbuf + (bt * 4 + j) * ZB_S + nt * 8;
            *(float4*)(zp)     = make_float4(acc[j][0], acc[j][1], acc[j][2], acc[j][3]);
            *(float4*)(zp + 4) = make_float4(acc[j][4], acc[j][5], acc[j][6], acc[j][7]);
        }
    } else if (nt == 12) {
        #pragma unroll
        for (int j = 0; j < 4; ++j) {
            float* zp = zbuf + (bt * 4 + j) * ZB_S + 96;
            *(float4*)(zp) = make_float4(acc[j][0], acc[j][1], acc[j][2], acc[j][3]);
        }
    }
    __syncthreads();
    if (tid < 64) {
        const int b_l = tid;
        const float* zrow = zbuf + b_l * ZB_S;
        float L[10];
        #pragma unroll
        for (int k = 0; k < NK; ++k) {
            float zkk[10];
            #pragma unroll
            for (int d = 0; d < 10; ++d) zkk[d] = zrow[k * 10 + d];
            const float* g = gp + k * 100;
            float a2 = 0.f;
            #pragma unroll
            for (int d1 = 0; d1 < 10; ++d1) {
                float t = 0.f;
                #pragma unroll
                for (int d2 = 0; d2 < 10; ++d2) t += g[d1 * 10 + d2] * zkk[d2];
                a2 += t * zkk[d1];
            }
            L[k] = a2;
        }
        float m = L[0];
        #pragma unroll
        for (int k = 1; k < NK; ++k) m = fmaxf(m, L[k]);
        float e[10], s = 0.f;
        #pragma unroll
        for (int k = 0; k < NK; ++k) { e[k] = __expf(L[k] - m); s += e[k]; }
        float inv = 1.0f / s;
        #pragma unroll
        for (int k = 0; k < NK; ++k) {
            float ck = e[k] * inv;
            #pragma unroll
            for (int d = 0; d < 10; ++d)
                wT[(k * 10 + d) * WT_S + b_l] = ck * zrow[k * 10 + d];
        }
    }
    const int Dt  = tid & 15;
    const int bt2 = tid >> 4;
    for (int c2 = 0; c2 < 4; ++c2) {
        __syncthreads();
        for (int p = tid; p < 640; p += 256) {
            int k = p >> 6, Dl = p & 63;
            const float* g = Us + ((size_t)((r * NK + k) * ND) + c2 * 64 + Dl) * NDL;
            float* dst = u2 + (k * NDL) * U2_S + Dl;
            #pragma unroll
            for (int d = 0; d < 10; ++d) dst[d * U2_S] = g[d];
        }
        __syncthreads();
        float o[4][4];
        #pragma unroll
        for (int j = 0; j < 4; ++j)
            #pragma unroll
            for (int i = 0; i < 4; ++i) o[j][i] = 0.f;
        #pragma unroll 4
        for (int n = 0; n < NN; ++n) {
            float4 wv = *(const float4*)(wT + n * WT_S + bt2 * 4);
            float4 uv = *(const float4*)(u2 + n * U2_S + Dt * 4);
            float wa[4] = {wv.x, wv.y, wv.z, wv.w};
            float ub[4] = {uv.x, uv.y, uv.z, uv.w};
            #pragma unroll
            for (int j = 0; j < 4; ++j)
                #pragma unroll
                for (int i = 0; i < 4; ++i) o[j][i] += wa[j] * ub[i];
        }
        #pragma unroll
        for (int j = 0; j < 4; ++j) {
            float* op = out + ((size_t)r * NB + b0 + bt2 * 4 + j) * ND + c2 * 64 + Dt * 4;
            *(float4*)op = make_float4(o[j][0], o[j][1], o[j][2], o[j][3]);
        }
    }
}

extern "C" void kernel_launch(void* const* d_in, const int* in_sizes, int n_in,
                              void* d_out, int out_size, void* d_ws, size_t ws_size,
                              hipStream_t stream) {
    const float* x  = (const float*)d_in[0];
    const float* Us = (const float*)d_in[1];
    float* out = (float*)d_out;

    if (ws_size >= (size_t)WS_NEED) {
        prep_kernel<<<dim3(336), 256, 0, stream>>>(x, Us, (char*)d_ws);
        ksub_occ<<<dim3(1024), 256, 0, stream>>>((const char*)d_ws, out);
    } else {
        gram_kernel<<<dim3(NR * NK), 128, 0, stream>>>(Us, (float*)d_ws);
        ksub_fused<<<dim3(NB / 64, NR), 256, 0, stream>>>(x, Us, (float*)d_ws, out);
    }
}

// Round 13
// 85.324 us; speedup vs baseline: 1.0642x; 1.0642x over previous
//
#include <hip/hip_runtime.h>
#include <math.h>

typedef unsigned short ushort_t;
typedef unsigned int uint32_tt;
typedef __attribute__((ext_vector_type(8))) short bf16x8;
typedef __attribute__((ext_vector_type(4))) float f32x4;

#define NR   8
#define NK   10
#define ND   256
#define NDL  10
#define NB   4096
#define NN   100
#define NP   128      // phase-1 padded n (8*16), rows 100..127 zero
#define NP2  128      // phase-3 padded K over n (4*32)

// ---- workspace layout (bytes) ---- (R15 layout, xb kept)
#define WS_GP   0                          // fp32 Gp[8][1000]
#define WS_XB   32768                      // bf16 x[4096][256] = 2,097,152
#define WS_U1   (32768 + 2097152)          // bf16 U1[8][128][256] = 524288
#define WS_U2   (WS_U1 + 524288)           // bf16 U2[8][256][128] = 524288
#define WS_NEED (WS_U2 + 524288)           // 3,178,496

// ---- ksub LDS layout (bytes) ----
#define L_US   0            // staged U half: 128 rows x 272B = 34816
#define L_ZB   34816        // zbuf: 2 tiles x 32 x 100 f32 = 25600 (wt overlay)
#define L_GP   60416        // gp: 1000 f32
#define L_SIZE 64416

__device__ __forceinline__ ushort_t f2bf(float f) {
    uint32_tt u = __float_as_uint(f);
    u = (u + 0x7FFF + ((u >> 16) & 1)) >> 16;   // RNE
    return (ushort_t)u;
}

// =====================================================================
// Prep, grid 336 x 256 (R15-verified, verbatim):
//  bid < 80 : one block per (r,k): Gram + U1 (128-row pad) + U2.
//  bid >= 80: 256 blocks, x->bf16 (xb kept — f32-direct x regressed
//             twice: R14, R16).
// =====================================================================
__global__ __launch_bounds__(256) void prep_kernel(const float* __restrict__ x,
                                                   const float* __restrict__ Us,
                                                   char* __restrict__ ws) {
    __shared__ float lu[ND * NDL];     // 10 KB, layout [D][d] stride 10
    const int bid = blockIdx.x, tid = threadIdx.x;

    if (bid >= 80) {
        ushort_t* xb = (ushort_t*)(ws + WS_XB);
        const int base = (bid - 80) * 1024;
        #pragma unroll
        for (int v = 0; v < 4; ++v) {
            int i = base + v * 256 + tid;
            float4 vv = ((const float4*)x)[i];
            uint32_tt p0 = (uint32_tt)f2bf(vv.x) | ((uint32_tt)f2bf(vv.y) << 16);
            uint32_tt p1 = (uint32_tt)f2bf(vv.z) | ((uint32_tt)f2bf(vv.w) << 16);
            ((uint2*)xb)[i] = make_uint2(p0, p1);
        }
        return;
    }

    const int rk = bid;                      // 0..79
    const int r  = rk / NK, k = rk - r * NK;
    const float* U = Us + (size_t)rk * ND * NDL;
    for (int i = tid; i < 640; i += 256)
        ((float4*)lu)[i] = ((const float4*)U)[i];
    __syncthreads();

    // ---- Gram: Gp = 10*I - 5*U^T U ----
    float* Gp = (float*)(ws + WS_GP);
    if (tid < NDL * NDL) {
        int d1 = tid / NDL, d2 = tid - d1 * NDL;
        float acc = 0.f;
        #pragma unroll 8
        for (int Di = 0; Di < ND; ++Di)
            acc += lu[Di * NDL + d1] * lu[Di * NDL + d2];
        Gp[(size_t)rk * 100 + tid] = (d1 == d2 ? 10.0f : 0.0f) - 5.0f * acc;
    }

    // ---- U1[r][k*10+d][D] bf16, coalesced in D ----
    ushort_t* u1 = (ushort_t*)(ws + WS_U1);
    for (int p = tid; p < ND * NDL; p += 256) {
        int d = p >> 8, D = p & 255;
        u1[((size_t)r * NP + k * NDL + d) * ND + D] = f2bf(lu[D * NDL + d]);
    }

    // ---- U2[r][D][k*10..k*10+10) bf16 ----
    ushort_t* u2 = (ushort_t*)(ws + WS_U2);
    {
        int D = tid;
        uint32_tt* dst = (uint32_tt*)(u2 + ((size_t)r * ND + D) * NP2 + k * NDL);
        const float* src = lu + D * NDL;
        #pragma unroll
        for (int j = 0; j < 5; ++j)
            dst[j] = (uint32_tt)f2bf(src[2 * j]) | ((uint32_tt)f2bf(src[2 * j + 1]) << 16);
    }

    // ---- zero pads (k==9 block only) ----
    if (k == NK - 1) {
        for (int p = tid; p < 28 * ND; p += 256) {
            int n = p >> 8, D = p & 255;
            u1[((size_t)r * NP + 100 + n) * ND + D] = 0;
        }
        uint32_tt* u2u = (uint32_tt*)u2;
        #pragma unroll
        for (int j = 0; j < 14; ++j)
            u2u[((size_t)r * ND + tid) * (NP2 / 2) + 50 + j] = 0;
    }
}

// =====================================================================
// R19 = R15 verbatim (measured session best: 85.95us).
//  (1) T14 async-STAGE split: each staging round's 8 global loads are
//      ISSUED one compute-phase early into registers; the ds_write
//      happens after the barrier.
//  (2) XCD swizzle: r = bid>>6, bt = bid&63. Same-bt blocks (sharing
//      x rows) share bid%8 => same XCD => xb L2-local.
// Grid 512, lb(256,2), LDS 64.4KB -> 2 blocks/CU (measured optimum:
// 1/CU=89.7 R17, 4/CU=90.8 R18, 2/CU=85.95 R15).
// =====================================================================
__global__ __launch_bounds__(256, 2) void ksub_mfma11(const char* __restrict__ ws,
                                                      float* __restrict__ out) {
    __shared__ __align__(16) char smem[L_SIZE];
    char*  usb = smem + L_US;
    float* gp  = (float*)(smem + L_GP);

    const int tid  = threadIdx.x;
    const int w    = tid >> 6;
    const int lane = tid & 63;
    const int c    = lane & 15;
    const int q    = lane >> 4;
    const int bid  = blockIdx.x;
    const int r    = bid >> 6;                 // XCD swizzle (see header)
    const int bt   = bid & 63;                 // 0..63
    const int b0   = bt * 64;
    const int wb   = w & 1;
    const int pair = w >> 1;                   // 0/1
    const int bloc = wb * 16 + c;              // 0..31

    const ushort_t* xbp = (const ushort_t*)(ws + WS_XB) + (size_t)(b0 + bloc) * ND + q * 8;
    const ushort_t* u1b = (const ushort_t*)(ws + WS_U1) + (size_t)r * NP * ND;
    const ushort_t* u2b = (const ushort_t*)(ws + WS_U2) + (size_t)r * ND * NP2;
    const float*    gpg = (const float*)(ws + WS_GP) + (size_t)r * 1000;

    for (int i = tid; i < 1000; i += 256) gp[i] = gpg[i];

    // stage-register buffers (32 VGPR each; one live per compute window)
    bf16x8 sA[8], sB[8];

    // lane->LDS mapping for staging (same for all stages)
    const int sn0 = tid >> 4;          // row for j=0 (rows advance by 16/j)
    const int sm  = tid & 15;          // 16B chunk within 256B row

    // ---- issue U1 h0 loads ----
    #pragma unroll
    for (int j = 0; j < 8; ++j)
        sA[j] = *(const bf16x8*)(u1b + (size_t)(sn0 + j * 16) * ND + sm * 8);

    // ---- xf h0 (bf16 xb; scattered but L2-local after swizzle) ----
    bf16x8 xf[2][4];
    #pragma unroll
    for (int tile = 0; tile < 2; ++tile)
        #pragma unroll
        for (int d = 0; d < 4; ++d)
            xf[tile][d] = *(const bf16x8*)(xbp + (size_t)tile * 32 * ND + d * 32);

    // ---- write U1 h0 ----
    #pragma unroll
    for (int j = 0; j < 8; ++j)
        *(bf16x8*)(usb + (sn0 + j * 16) * 272 + sm * 16) = sA[j];
    __syncthreads();

    // ---- issue U1 h1 loads (in flight during h0 MFMA) ----
    #pragma unroll
    for (int j = 0; j < 8; ++j)
        sB[j] = *(const bf16x8*)(u1b + 128 + (size_t)(sn0 + j * 16) * ND + sm * 8);

    f32x4 acc1[2][4];
    #pragma unroll
    for (int t2 = 0; t2 < 2; ++t2)
        #pragma unroll
        for (int tt = 0; tt < 4; ++tt) acc1[t2][tt] = (f32x4){0.f, 0.f, 0.f, 0.f};

    // ---- MFMA h0 ----
    #pragma unroll
    for (int tt = 0; tt < 4; ++tt) {
        const int t = pair * 4 + tt;
        #pragma unroll
        for (int d = 0; d < 4; ++d) {
            bf16x8 uf = *(const bf16x8*)(usb + (t * 16 + c) * 272 + d * 64 + q * 16);
            acc1[0][tt] = __builtin_amdgcn_mfma_f32_16x16x32_bf16(uf, xf[0][d], acc1[0][tt], 0, 0, 0);
            acc1[1][tt] = __builtin_amdgcn_mfma_f32_16x16x32_bf16(uf, xf[1][d], acc1[1][tt], 0, 0, 0);
        }
    }
    __syncthreads();               // h0 usb reads done

    // ---- write U1 h1; xf h1 ----
    #pragma unroll
    for (int j = 0; j < 8; ++j)
        *(bf16x8*)(usb + (sn0 + j * 16) * 272 + sm * 16) = sB[j];
    #pragma unroll
    for (int tile = 0; tile < 2; ++tile)
        #pragma unroll
        for (int d = 0; d < 4; ++d)
            xf[tile][d] = *(const bf16x8*)(xbp + (size_t)tile * 32 * ND + (4 + d) * 32);
    __syncthreads();

    // ---- issue U2 h0 loads (in flight during h1 MFMA + zdump) ----
    #pragma unroll
    for (int j = 0; j < 8; ++j)
        sA[j] = *(const bf16x8*)(u2b + (size_t)(sn0 + j * 16) * NP2 + sm * 8);

    // ---- MFMA h1 ----
    #pragma unroll
    for (int tt = 0; tt < 4; ++tt) {
        const int t = pair * 4 + tt;
        #pragma unroll
        for (int d = 0; d < 4; ++d) {
            bf16x8 uf = *(const bf16x8*)(usb + (t * 16 + c) * 272 + d * 64 + q * 16);
            acc1[0][tt] = __builtin_amdgcn_mfma_f32_16x16x32_bf16(uf, xf[0][d], acc1[0][tt], 0, 0, 0);
            acc1[1][tt] = __builtin_amdgcn_mfma_f32_16x16x32_bf16(uf, xf[1][d], acc1[1][tt], 0, 0, 0);
        }
    }

    // ---- dump Z^T C-frags: row n = t*16+q*4+rg, col b = bloc, 2 tiles ----
    #pragma unroll
    for (int tile = 0; tile < 2; ++tile) {
        float* zb = (float*)(smem + L_ZB + tile * 12800);
        #pragma unroll
        for (int tt = 0; tt < 4; ++tt) {
            int t = pair * 4 + tt;
            #pragma unroll
            for (int rg = 0; rg < 4; ++rg) {
                int n = t * 16 + q * 4 + rg;
                if (n < NN) zb[bloc * 100 + n] = acc1[tile][tt][rg];
            }
        }
    }
    __syncthreads();               // zbuf ready; phase-1 usb reads done

    // ---- write U2 h0 into usb now (visible via softmax's barriers) ----
    #pragma unroll
    for (int j = 0; j < 8; ++j)
        *(bf16x8*)(usb + (sn0 + j * 16) * 272 + sm * 16) = sA[j];

    // ================= softmax per tile (R0-proven body) =================
    const int bsm = tid >> 3;
    const int kq  = tid & 7;
    #pragma unroll 1
    for (int tile = 0; tile < 2; ++tile) {
        float*    zb = (float*)(smem + L_ZB + tile * 12800);
        ushort_t* wt = (ushort_t*)(smem + L_ZB + tile * 8704);
        float zk[2][10], ee[2];
        {
            const float* zr = zb + bsm * 100;
            float L[2];
            #pragma unroll
            for (int jj = 0; jj < 2; ++jj) {
                int k = kq + 8 * jj;
                L[jj] = -1e30f;
                if (k < NK) {
                    #pragma unroll
                    for (int d = 0; d < 10; ++d) zk[jj][d] = zr[k * 10 + d];
                    const float* g = gp + k * 100;
                    float acc = 0.f;
                    #pragma unroll
                    for (int d1 = 0; d1 < 10; ++d1) {
                        float t2 = 0.f;
                        #pragma unroll
                        for (int d2 = 0; d2 < 10; ++d2) t2 += g[d1 * 10 + d2] * zk[jj][d2];
                        acc += t2 * zk[jj][d1];
                    }
                    L[jj] = acc;
                }
            }
            float m = fmaxf(L[0], L[1]);
            m = fmaxf(m, __shfl_xor(m, 1));
            m = fmaxf(m, __shfl_xor(m, 2));
            m = fmaxf(m, __shfl_xor(m, 4));
            float s = 0.f;
            #pragma unroll
            for (int jj = 0; jj < 2; ++jj) {
                ee[jj] = (kq + 8 * jj < NK) ? __expf(L[jj] - m) : 0.f;
                s += ee[jj];
            }
            s += __shfl_xor(s, 1);
            s += __shfl_xor(s, 2);
            s += __shfl_xor(s, 4);
            float inv = 1.0f / s;
            #pragma unroll
            for (int jj = 0; jj < 2; ++jj) ee[jj] *= inv;
        }
        __syncthreads();           // zb reads done; wt overlay safe

        #pragma unroll
        for (int jj = 0; jj < 2; ++jj) {
            int k = kq + 8 * jj;
            if (k < NK) {
                #pragma unroll
                for (int d = 0; d < 10; ++d)
                    wt[bsm * 136 + k * 10 + d] = f2bf(ee[jj] * zk[jj][d]);
            }
        }
        // zero-pad wt n in [100,128): 14 uints per row, 32 rows
        {
            int row = tid >> 4, p = tid & 15;
            if (row < 32 && p < 14) ((uint32_tt*)wt)[row * 68 + 50 + p] = 0;
            row = (tid + 256) >> 4;
            if (row < 32 && p < 14) ((uint32_tt*)wt)[row * 68 + 50 + p] = 0;
        }
    }
    __syncthreads();               // wt complete; U2h0 ds_writes visible

    // ================= phase 3: out = U2 w, two D-halves =================
    const ushort_t* wt0 = (ushort_t*)(smem + L_ZB);
    const ushort_t* wt1 = (ushort_t*)(smem + L_ZB + 8704);
    const size_t orow = (size_t)r * NB + b0;

    // ---- issue U2 h1 loads (in flight during phase3 h0) ----
    #pragma unroll
    for (int j = 0; j < 8; ++j)
        sB[j] = *(const bf16x8*)(u2b + (size_t)(128 + sn0 + j * 16) * NP2 + sm * 8);

    // ---- h0 MFMAs + stores ----
    {
        f32x4 acc3[2][4];
        #pragma unroll
        for (int t2 = 0; t2 < 2; ++t2)
            #pragma unroll
            for (int jj = 0; jj < 4; ++jj) acc3[t2][jj] = (f32x4){0.f, 0.f, 0.f, 0.f};

        #pragma unroll
        for (int nc = 0; nc < 4; ++nc) {
            bf16x8 bf0 = *(const bf16x8*)(wt0 + bloc * 136 + nc * 32 + q * 8);
            bf16x8 bf1 = *(const bf16x8*)(wt1 + bloc * 136 + nc * 32 + q * 8);
            #pragma unroll
            for (int jj = 0; jj < 4; ++jj) {
                bf16x8 af = *(const bf16x8*)(usb + (pair * 64 + jj * 16 + c) * 272 + nc * 64 + q * 16);
                acc3[0][jj] = __builtin_amdgcn_mfma_f32_16x16x32_bf16(af, bf0, acc3[0][jj], 0, 0, 0);
                acc3[1][jj] = __builtin_amdgcn_mfma_f32_16x16x32_bf16(af, bf1, acc3[1][jj], 0, 0, 0);
            }
        }
        #pragma unroll
        for (int tile = 0; tile < 2; ++tile)
            #pragma unroll
            for (int jj = 0; jj < 4; ++jj)
                __builtin_nontemporal_store(acc3[tile][jj],
                    (f32x4*)(out + (orow + tile * 32 + bloc) * ND + pair * 64 + jj * 16 + q * 4));
    }
    __syncthreads();               // h0 usb reads done

    // ---- write U2 h1 ----
    #pragma unroll
    for (int j = 0; j < 8; ++j)
        *(bf16x8*)(usb + (sn0 + j * 16) * 272 + sm * 16) = sB[j];
    __syncthreads();

    // ---- h1 MFMAs + stores ----
    {
        f32x4 acc3[2][4];
        #pragma unroll
        for (int t2 = 0; t2 < 2; ++t2)
            #pragma unroll
            for (int jj = 0; jj < 4; ++jj) acc3[t2][jj] = (f32x4){0.f, 0.f, 0.f, 0.f};

        #pragma unroll
        for (int nc = 0; nc < 4; ++nc) {
            bf16x8 bf0 = *(const bf16x8*)(wt0 + bloc * 136 + nc * 32 + q * 8);
            bf16x8 bf1 = *(const bf16x8*)(wt1 + bloc * 136 + nc * 32 + q * 8);
            #pragma unroll
            for (int jj = 0; jj < 4; ++jj) {
                bf16x8 af = *(const bf16x8*)(usb + (pair * 64 + jj * 16 + c) * 272 + nc * 64 + q * 16);
                acc3[0][jj] = __builtin_amdgcn_mfma_f32_16x16x32_bf16(af, bf0, acc3[0][jj], 0, 0, 0);
                acc3[1][jj] = __builtin_amdgcn_mfma_f32_16x16x32_bf16(af, bf1, acc3[1][jj], 0, 0, 0);
            }
        }
        #pragma unroll
        for (int tile = 0; tile < 2; ++tile)
            #pragma unroll
            for (int jj = 0; jj < 4; ++jj)
                __builtin_nontemporal_store(acc3[tile][jj],
                    (f32x4*)(out + (orow + tile * 32 + bloc) * ND + 128 + pair * 64 + jj * 16 + q * 4));
    }
}

// =====================================================================
// Fallback (round-2 verified path) if ws is too small for staging
// =====================================================================
#define XS_S 68
#define US_S 132
#define ZB_S 104
#define WT_S 68
#define U2_S 68
#define OFF_WT 0
#define OFF_SH 6800
#define OFF_GP 13600
#define SMEM_F 14600

__global__ __launch_bounds__(128) void gram_kernel(const float* __restrict__ Us,
                                                   float* __restrict__ Gp) {
    int rk = blockIdx.x;
    const float* U = Us + (size_t)rk * ND * NDL;
    __shared__ float u[ND * NDL];
    for (int i = threadIdx.x; i < ND * NDL; i += blockDim.x) u[i] = U[i];
    __syncthreads();
    int e = threadIdx.x;
    if (e < NDL * NDL) {
        int d1 = e / NDL, d2 = e % NDL;
        float acc = 0.f;
        #pragma unroll 8
        for (int Di = 0; Di < ND; ++Di)
            acc += u[Di * NDL + d1] * u[Di * NDL + d2];
        Gp[(size_t)rk * (NDL * NDL) + e] = (d1 == d2 ? 10.0f : 0.0f) - 5.0f * acc;
    }
}

__global__ __launch_bounds__(256, 2) void ksub_fused(const float* __restrict__ x,
                                                     const float* __restrict__ Us,
                                                     const float* __restrict__ Gp,
                                                     float* __restrict__ out) {
    __shared__ float smemf[SMEM_F];
    float* wT   = smemf + OFF_WT;
    float* xsf  = smemf + OFF_SH;
    float* usf  = smemf + OFF_SH + 2176;
    float* zbuf = smemf + OFF_SH;
    float* u2   = smemf + OFF_SH;
    float* gp   = smemf + OFF_GP;

    const int tid = threadIdx.x;
    const int r   = blockIdx.y;
    const int b0  = blockIdx.x * 64;

    for (int i = tid; i < NK * NDL * NDL; i += 256)
        gp[i] = Gp[(size_t)r * (NK * NDL * NDL) + i];

    const int nt = tid & 15;
    const int bt = tid >> 4;
    float acc[4][8];
    #pragma unroll
    for (int j = 0; j < 4; ++j)
        #pragma unroll
        for (int i = 0; i < 8; ++i) acc[j][i] = 0.f;

    for (int cch = 0; cch < 8; ++cch) {
        __syncthreads();
        for (int i = tid; i < 512; i += 256) {
            int b = i >> 3, f = i & 7;
            float4 v = ((const float4*)(x + (size_t)(b0 + b) * ND))[cch * 8 + f];
            float* dst = xsf + (f * 4) * XS_S + b;
            dst[0] = v.x; dst[XS_S] = v.y; dst[2 * XS_S] = v.z; dst[3 * XS_S] = v.w;
        }
        for (int p = tid; p < 320; p += 256) {
            int k = p >> 5, Dl = p & 31;
            const float* g = Us + ((size_t)((r * NK + k) * ND) + cch * 32 + Dl) * NDL;
            float* dst = usf + Dl * US_S + k * NDL;
            #pragma unroll
            for (int d = 0; d < 10; ++d) dst[d] = g[d];
        }
        __syncthreads();
        #pragma unroll 4
        for (int Dl = 0; Dl < 32; ++Dl) {
            float4 xv = *(const float4*)(xsf + Dl * XS_S + bt * 4);
            float4 ua = *(const float4*)(usf + Dl * US_S + nt * 8);
            float4 ub = *(const float4*)(usf + Dl * US_S + nt * 8 + 4);
            float xa[4] = {xv.x, xv.y, xv.z, xv.w};
            float uu[8] = {ua.x, ua.y, ua.z, ua.w, ub.x, ub.y, ub.z, ub.w};
            #pragma unroll
            for (int j = 0; j < 4; ++j)
                #pragma unroll
                for (int i = 0; i < 8; ++i) acc[j][i] += xa[j] * uu[i];
        }
    }
    __syncthreads();
    if (nt < 12) {
        #pragma unroll
        for (int j = 0; j < 4; ++j) {
            float* zp = zbuf + (bt * 4 + j) * ZB_S + nt * 8;
            *(float4*)(zp)     = make_float4(acc[j][0], acc[j][1], acc[j][2], acc[j][3]);
            *(float4*)(zp + 4) = make_float4(acc[j][4], acc[j][5], acc[j][6], acc[j][7]);
        }
    } else if (nt == 12) {
        #pragma unroll
        for (int j = 0; j < 4; ++j) {
            float* zp = zbuf + (bt * 4 + j) * ZB_S + 96;
            *(float4*)(zp) = make_float4(acc[j][0], acc[j][1], acc[j][2], acc[j][3]);
        }
    }
    __syncthreads();
    if (tid < 64) {
        const int b_l = tid;
        const float* zrow = zbuf + b_l * ZB_S;
        float L[10];
        #pragma unroll
        for (int k = 0; k < NK; ++k) {
            float zkk[10];
            #pragma unroll
            for (int d = 0; d < 10; ++d) zkk[d] = zrow[k * 10 + d];
            const float* g = gp + k * 100;
            float a2 = 0.f;
            #pragma unroll
            for (int d1 = 0; d1 < 10; ++d1) {
                float t = 0.f;
                #pragma unroll
                for (int d2 = 0; d2 < 10; ++d2) t += g[d1 * 10 + d2] * zkk[d2];
                a2 += t * zkk[d1];
            }
            L[k] = a2;
        }
        float m = L[0];
        #pragma unroll
        for (int k = 1; k < NK; ++k) m = fmaxf(m, L[k]);
        float e[10], s = 0.f;
        #pragma unroll
        for (int k = 0; k < NK; ++k) { e[k] = __expf(L[k] - m); s += e[k]; }
        float inv = 1.0f / s;
        #pragma unroll
        for (int k = 0; k < NK; ++k) {
            float ck = e[k] * inv;
            #pragma unroll
            for (int d = 0; d < 10; ++d)
                wT[(k * 10 + d) * WT_S + b_l] = ck * zrow[k * 10 + d];
        }
    }
    const int Dt  = tid & 15;
    const int bt2 = tid >> 4;
    for (int c2 = 0; c2 < 4; ++c2) {
        __syncthreads();
        for (int p = tid; p < 640; p += 256) {
            int k = p >> 6, Dl = p & 63;
            const float* g = Us + ((size_t)((r * NK + k) * ND) + c2 * 64 + Dl) * NDL;
            float* dst = u2 + (k * NDL) * U2_S + Dl;
            #pragma unroll
            for (int d = 0; d < 10; ++d) dst[d * U2_S] = g[d];
        }
        __syncthreads();
        float o[4][4];
        #pragma unroll
        for (int j = 0; j < 4; ++j)
            #pragma unroll
            for (int i = 0; i < 4; ++i) o[j][i] = 0.f;
        #pragma unroll 4
        for (int n = 0; n < NN; ++n) {
            float4 wv = *(const float4*)(wT + n * WT_S + bt2 * 4);
            float4 uv = *(const float4*)(u2 + n * U2_S + Dt * 4);
            float wa[4] = {wv.x, wv.y, wv.z, wv.w};
            float ub[4] = {uv.x, uv.y, uv.z, uv.w};
            #pragma unroll
            for (int j = 0; j < 4; ++j)
                #pragma unroll
                for (int i = 0; i < 4; ++i) o[j][i] += wa[j] * ub[i];
        }
        #pragma unroll
        for (int j = 0; j < 4; ++j) {
            float* op = out + ((size_t)r * NB + b0 + bt2 * 4 + j) * ND + c2 * 64 + Dt * 4;
            *(float4*)op = make_float4(o[j][0], o[j][1], o[j][2], o[j][3]);
        }
    }
}

extern "C" void kernel_launch(void* const* d_in, const int* in_sizes, int n_in,
                              void* d_out, int out_size, void* d_ws, size_t ws_size,
                              hipStream_t stream) {
    const float* x  = (const float*)d_in[0];
    const float* Us = (const float*)d_in[1];
    float* out = (float*)d_out;

    if (ws_size >= (size_t)WS_NEED) {
        prep_kernel<<<dim3(336), 256, 0, stream>>>(x, Us, (char*)d_ws);
        ksub_mfma11<<<dim3(512), 256, 0, stream>>>((const char*)d_ws, out);
    } else {
        gram_kernel<<<dim3(NR * NK), 128, 0, stream>>>(Us, (float*)d_ws);
        ksub_fused<<<dim3(NB / 64, NR), 256, 0, stream>>>(x, Us, (float*)d_ws, out);
    }
}